// Round 2
// baseline (467.221 us; speedup 1.0000x reference)
//
#include <hip/hip_runtime.h>
#include <hip/hip_bf16.h>
#include <stdint.h>

typedef __bf16 bf16_t;
typedef __bf16 bf16x8 __attribute__((ext_vector_type(8)));
typedef __bf16 bf16x4 __attribute__((ext_vector_type(4)));
typedef float f32x4 __attribute__((ext_vector_type(4)));

static constexpr int TT = 2048, CC = 1024;

__device__ __forceinline__ void gld_lds16(const void* g, void* l) {
  __builtin_amdgcn_global_load_lds((const __attribute__((address_space(1))) void*)g,
                                   (__attribute__((address_space(3))) void*)l, 16, 0, 0);
}

// out[n][k] = (bf16) in[k][n]; per-batch stride K*N both sides
__global__ __launch_bounds__(256) void transpose_cvt(const float* __restrict__ in,
                                                     bf16_t* __restrict__ out,
                                                     int K, int N) {
  __shared__ float t[32][33];
  const int k0 = blockIdx.x * 32, n0 = blockIdx.y * 32;
  const size_t boff = (size_t)blockIdx.z * K * N;
  in += boff;
  out += boff;
  const int tx = threadIdx.x & 31, ty = threadIdx.x >> 5;
#pragma unroll
  for (int j = 0; j < 4; ++j)
    t[ty + j * 8][tx] = in[(size_t)(k0 + ty + j * 8) * N + n0 + tx];
  __syncthreads();
#pragma unroll
  for (int j = 0; j < 4; ++j)
    out[(size_t)(n0 + ty + j * 8) * K + k0 + tx] = (bf16_t)t[tx][ty + j * 8];
}

// LayerNorm over C=1024, one block (256 thr) per row, bf16 out
__global__ __launch_bounds__(256) void ln_f32_bf16(const float* __restrict__ x,
                                                   const float* __restrict__ g,
                                                   const float* __restrict__ b,
                                                   bf16_t* __restrict__ out) {
  const int row = blockIdx.x;
  const int tid = threadIdx.x;
  const float4 v = ((const float4*)(x + (size_t)row * CC))[tid];
  float s = v.x + v.y + v.z + v.w;
  float q = v.x * v.x + v.y * v.y + v.z * v.z + v.w * v.w;
#pragma unroll
  for (int off = 1; off < 64; off <<= 1) {
    s += __shfl_xor(s, off);
    q += __shfl_xor(q, off);
  }
  __shared__ float red[8];
  const int wave = tid >> 6, lane = tid & 63;
  if (lane == 0) { red[wave] = s; red[4 + wave] = q; }
  __syncthreads();
  s = red[0] + red[1] + red[2] + red[3];
  q = red[4] + red[5] + red[6] + red[7];
  const float mu = s * (1.0f / CC);
  float var = q * (1.0f / CC) - mu * mu;
  var = fmaxf(var, 0.f);
  const float rstd = rsqrtf(var + 1e-5f);
  const float4 gv = ((const float4*)g)[tid];
  const float4 bv = ((const float4*)b)[tid];
  bf16x4 o;
  o[0] = (bf16_t)((v.x - mu) * rstd * gv.x + bv.x);
  o[1] = (bf16_t)((v.y - mu) * rstd * gv.y + bv.y);
  o[2] = (bf16_t)((v.z - mu) * rstd * gv.z + bv.z);
  o[3] = (bf16_t)((v.w - mu) * rstd * gv.w + bv.w);
  *(bf16x4*)(out + (size_t)row * CC + tid * 4) = o;
}

// C = A[M,K] @ Bt[N,K]^T ; A,Bt bf16 row-major. 128x128 tile, BK=32, 4 waves.
// EPI: 0 = bf16 store; 1 = bf16 store of relu(acc+bias); 2 = f32 store of acc+bias+res
template <int EPI>
__global__ __launch_bounds__(256) void gemm_bt(const bf16_t* __restrict__ A,
                                               const bf16_t* __restrict__ Bt,
                                               void* __restrict__ Cout,
                                               const float* __restrict__ bias,
                                               const float* __restrict__ res,
                                               int M, int N, int K) {
  __shared__ alignas(16) bf16_t As[128 * 32];
  __shared__ alignas(16) bf16_t Bs[128 * 32];
  const int tid = threadIdx.x;
  const int wave = tid >> 6, lane = tid & 63;
  const int lr = lane & 15, lg = lane >> 4;
  const int wm = wave >> 1, wn = wave & 1;
  const int tm0 = blockIdx.y * 128, tn0 = blockIdx.x * 128;

  // staging: wave w, chunk j in {0,1}: LDS elems (w*2+j)*512 + lane*8
  //          maps to row=(w*2+j)*16 + lane/4, kcol=(lane%4)*8 of the [128][32] tile
  const int r0 = wave * 32 + (lane >> 2);
  const int kc = (lane & 3) * 8;
  const bf16_t* Ag0 = A + (size_t)(tm0 + r0) * K + kc;
  const bf16_t* Ag1 = Ag0 + (size_t)16 * K;
  const bf16_t* Bg0 = Bt + (size_t)(tn0 + r0) * K + kc;
  const bf16_t* Bg1 = Bg0 + (size_t)16 * K;
  bf16_t* Al = As + (size_t)(wave * 2) * 512;
  bf16_t* Bl = Bs + (size_t)(wave * 2) * 512;

  f32x4 acc[4][4] = {};
  for (int k0 = 0; k0 < K; k0 += 32) {
    gld_lds16(Ag0 + k0, Al);
    gld_lds16(Ag1 + k0, Al + 512);
    gld_lds16(Bg0 + k0, Bl);
    gld_lds16(Bg1 + k0, Bl + 512);
    __syncthreads();
    bf16x8 af[4], bfr[4];
#pragma unroll
    for (int m = 0; m < 4; ++m)
      af[m] = *(const bf16x8*)&As[(wm * 64 + m * 16 + lr) * 32 + lg * 8];
#pragma unroll
    for (int n = 0; n < 4; ++n)
      bfr[n] = *(const bf16x8*)&Bs[(wn * 64 + n * 16 + lr) * 32 + lg * 8];
#pragma unroll
    for (int m = 0; m < 4; ++m)
#pragma unroll
      for (int n = 0; n < 4; ++n)
        acc[m][n] = __builtin_amdgcn_mfma_f32_16x16x32_bf16(af[m], bfr[n], acc[m][n], 0, 0, 0);
    __syncthreads();
  }
#pragma unroll
  for (int m = 0; m < 4; ++m) {
#pragma unroll
    for (int i = 0; i < 4; ++i) {
      const int row = tm0 + wm * 64 + m * 16 + lg * 4 + i;
#pragma unroll
      for (int n = 0; n < 4; ++n) {
        const int col = tn0 + wn * 64 + n * 16 + lr;
        float v = acc[m][n][i];
        if (EPI == 1) v = fmaxf(v + bias[col], 0.f);
        if (EPI == 2) v = v + bias[col] + res[(size_t)row * N + col];
        if (EPI == 2)
          ((float*)Cout)[(size_t)row * N + col] = v;
        else
          ((bf16_t*)Cout)[(size_t)row * N + col] = (bf16_t)v;
      }
    }
  }
}

// Flash attention, causal, D=64, T=2048. qkv: [B*T][3072] bf16, q|k|v each 1024 wide
// (head h at col h*64). O: [B*T][1024] bf16. Block: 4 waves, 64 q-rows. scale = 1/32.
__global__ __launch_bounds__(256) void attn_fwd(const bf16_t* __restrict__ qkv,
                                                bf16_t* __restrict__ O) {
  const int bh = blockIdx.y;
  const int bb = bh >> 4, hh = bh & 15;
  const int qbase = blockIdx.x * 64;
  const int tid = threadIdx.x;
  const int wave = tid >> 6, lane = tid & 63;
  const int lr = lane & 15, lg = lane >> 4;
  const bf16_t* Qp = qkv + (size_t)bb * TT * 3072 + hh * 64;
  const bf16_t* Kp = Qp + 1024;
  const bf16_t* Vp = Qp + 2048;

  __shared__ alignas(16) bf16_t VtS[64][32];     // V^T tile: [d][s]
  __shared__ alignas(16) bf16_t PlS[4][16][32];  // per-wave P tile

  const int qrow = qbase + wave * 16;
  const bf16x8 qf0 = *(const bf16x8*)(Qp + (size_t)(qrow + lr) * 3072 + lg * 8);
  const bf16x8 qf1 = *(const bf16x8*)(Qp + (size_t)(qrow + lr) * 3072 + 32 + lg * 8);

  f32x4 oacc[4] = {};
  float m_r[4], l_r[4];
#pragma unroll
  for (int i = 0; i < 4; ++i) { m_r[i] = -1e38f; l_r[i] = 0.f; }

  const float scale = 0.03125f;  // 1024^-0.5
  const int smax = qbase + 64;
  const int vs = tid >> 3;       // 0..31
  const int vd = (tid & 7) * 8;  // 0..56

  for (int s0 = 0; s0 < smax; s0 += 32) {
    __syncthreads();  // previous iter's Vt readers done
    const bf16x8 vv = *(const bf16x8*)(Vp + (size_t)(s0 + vs) * 3072 + vd);
#pragma unroll
    for (int j = 0; j < 8; ++j) VtS[vd + j][vs] = vv[j];
    __syncthreads();

    if (s0 <= qrow + 15) {
      float P[2][4];
#pragma unroll
      for (int ct = 0; ct < 2; ++ct) {
        const bf16_t* Kr = Kp + (size_t)(s0 + ct * 16 + lr) * 3072;
        const bf16x8 kf0 = *(const bf16x8*)(Kr + lg * 8);
        const bf16x8 kf1 = *(const bf16x8*)(Kr + 32 + lg * 8);
        f32x4 z = {};
        z = __builtin_amdgcn_mfma_f32_16x16x32_bf16(qf0, kf0, z, 0, 0, 0);
        z = __builtin_amdgcn_mfma_f32_16x16x32_bf16(qf1, kf1, z, 0, 0, 0);
        const int sg = s0 + ct * 16 + lr;
#pragma unroll
        for (int i = 0; i < 4; ++i) {
          float sv = z[i] * scale;
          if (sg > qrow + lg * 4 + i) sv = -1e30f;  // causal mask
          P[ct][i] = sv;
        }
      }
      float rm[4];
#pragma unroll
      for (int i = 0; i < 4; ++i) rm[i] = fmaxf(P[0][i], P[1][i]);
#pragma unroll
      for (int off = 1; off < 16; off <<= 1)
#pragma unroll
        for (int i = 0; i < 4; ++i) rm[i] = fmaxf(rm[i], __shfl_xor(rm[i], off));
      float alpha[4], lad[4];
#pragma unroll
      for (int i = 0; i < 4; ++i) {
        const float mn = fmaxf(m_r[i], rm[i]);
        alpha[i] = __expf(m_r[i] - mn);
        m_r[i] = mn;
        const float p0 = __expf(P[0][i] - mn);
        const float p1 = __expf(P[1][i] - mn);
        P[0][i] = p0;
        P[1][i] = p1;
        lad[i] = p0 + p1;
      }
#pragma unroll
      for (int off = 1; off < 16; off <<= 1)
#pragma unroll
        for (int i = 0; i < 4; ++i) lad[i] += __shfl_xor(lad[i], off);
#pragma unroll
      for (int i = 0; i < 4; ++i) l_r[i] = l_r[i] * alpha[i] + lad[i];
#pragma unroll
      for (int ct = 0; ct < 2; ++ct)
#pragma unroll
        for (int i = 0; i < 4; ++i)
          PlS[wave][lg * 4 + i][ct * 16 + lr] = (bf16_t)P[ct][i];
      asm volatile("s_waitcnt lgkmcnt(0)" ::: "memory");
      const bf16x8 pf = *(const bf16x8*)&PlS[wave][lr][lg * 8];
#pragma unroll
      for (int db = 0; db < 4; ++db)
#pragma unroll
        for (int i = 0; i < 4; ++i) oacc[db][i] *= alpha[i];
#pragma unroll
      for (int db = 0; db < 4; ++db) {
        const bf16x8 vf = *(const bf16x8*)&VtS[db * 16 + lr][lg * 8];
        oacc[db] = __builtin_amdgcn_mfma_f32_16x16x32_bf16(pf, vf, oacc[db], 0, 0, 0);
      }
    }
  }

  bf16_t* Op = O + ((size_t)bb * TT + qrow) * CC + hh * 64;
#pragma unroll
  for (int db = 0; db < 4; ++db)
#pragma unroll
    for (int i = 0; i < 4; ++i)
      Op[(size_t)(lg * 4 + i) * CC + db * 16 + lr] = (bf16_t)(oacc[db][i] / l_r[i]);
}

extern "C" void kernel_launch(void* const* d_in, const int* in_sizes, int n_in,
                              void* d_out, int out_size, void* d_ws, size_t ws_size,
                              hipStream_t stream) {
  const float* x      = (const float*)d_in[0];
  const float* wq     = (const float*)d_in[1];
  const float* wk     = (const float*)d_in[2];
  const float* wv     = (const float*)d_in[3];
  const float* w_proj = (const float*)d_in[4];
  const float* b_proj = (const float*)d_in[5];
  const float* w1     = (const float*)d_in[6];
  const float* b1     = (const float*)d_in[7];
  const float* w2     = (const float*)d_in[8];
  const float* b2     = (const float*)d_in[9];
  const float* ln1_g  = (const float*)d_in[10];
  const float* ln1_b  = (const float*)d_in[11];
  const float* ln2_g  = (const float*)d_in[12];
  const float* ln2_b  = (const float*)d_in[13];

  char* ws = (char*)d_ws;
  const size_t MB = 1024 * 1024;
  bf16_t* h1    = (bf16_t*)(ws + 0);         // 8 MB  [4096][1024]
  bf16_t* Bqkv  = (bf16_t*)(ws + 8 * MB);    // 6 MB  [3072][1024]
  bf16_t* Bproj = (bf16_t*)(ws + 14 * MB);   // 2 MB  [1024][1024]
  bf16_t* B1w   = (bf16_t*)(ws + 16 * MB);   // 8 MB  [4096][1024]
  bf16_t* B2w   = (bf16_t*)(ws + 24 * MB);   // 8 MB  [1024][4096]
  bf16_t* qkv   = (bf16_t*)(ws + 32 * MB);   // 24 MB [4096][3072]
  bf16_t* Obuf  = (bf16_t*)(ws + 56 * MB);   // 8 MB  [4096][1024]
  float*  res1  = (float*)(ws + 64 * MB);    // 16 MB [4096][1024]
  bf16_t* h2    = (bf16_t*)(ws + 80 * MB);   // 8 MB  [4096][1024]
  bf16_t* a1    = (bf16_t*)(ws + 32 * MB);   // 32 MB [4096][4096], reuses qkv+Obuf
  float*  outp  = (float*)d_out;

  dim3 blk(256);
  // weight prep: Bt[n][k] layouts
  transpose_cvt<<<dim3(32, 2, 16), blk, 0, stream>>>(wq, Bqkv, 1024, 64);
  transpose_cvt<<<dim3(32, 2, 16), blk, 0, stream>>>(wk, Bqkv + 1024 * 1024, 1024, 64);
  transpose_cvt<<<dim3(32, 2, 16), blk, 0, stream>>>(wv, Bqkv + 2 * 1024 * 1024, 1024, 64);
  transpose_cvt<<<dim3(32, 32, 1), blk, 0, stream>>>(w_proj, Bproj, 1024, 1024);
  transpose_cvt<<<dim3(32, 128, 1), blk, 0, stream>>>(w1, B1w, 1024, 4096);
  transpose_cvt<<<dim3(128, 32, 1), blk, 0, stream>>>(w2, B2w, 4096, 1024);

  ln_f32_bf16<<<dim3(4096), blk, 0, stream>>>(x, ln1_g, ln1_b, h1);
  gemm_bt<0><<<dim3(24, 32), blk, 0, stream>>>(h1, Bqkv, qkv, nullptr, nullptr, 4096, 3072, 1024);
  attn_fwd<<<dim3(32, 32), blk, 0, stream>>>(qkv, Obuf);
  gemm_bt<2><<<dim3(8, 32), blk, 0, stream>>>(Obuf, Bproj, res1, b_proj, x, 4096, 1024, 1024);
  ln_f32_bf16<<<dim3(4096), blk, 0, stream>>>(res1, ln2_g, ln2_b, h2);
  gemm_bt<1><<<dim3(32, 32), blk, 0, stream>>>(h2, B1w, a1, b1, nullptr, 4096, 4096, 1024);
  gemm_bt<2><<<dim3(8, 32), blk, 0, stream>>>(a1, B2w, outp, b2, res1, 4096, 1024, 4096);
}